// Round 3
// baseline (1689.224 us; speedup 1.0000x reference)
//
#include <hip/hip_runtime.h>
#include <math.h>

typedef unsigned short ushort_t;
typedef __attribute__((ext_vector_type(8))) short short8;   // 8 bf16 in 4 VGPRs
typedef __attribute__((ext_vector_type(4))) float f32x4;

#define T_LEN 1024
#define BATCH 4
#define CDIM  1024
#define NHEAD 16
#define HDIM  64
#define TQ    8

static __device__ __forceinline__ float b2f(ushort_t u) {
  union { unsigned int i; float f; } x;
  x.i = ((unsigned int)u) << 16;
  return x.f;
}
// fp32 -> bf16 bits, round-to-nearest-even
static __device__ __forceinline__ ushort_t f2b(float f) {
  unsigned int x = __float_as_uint(f);
  unsigned int r = (x + 0x7fffu + ((x >> 16) & 1u)) >> 16;
  return (ushort_t)r;
}

// exact T5 bucket (verified vs fp32-log reference at all boundaries: a=16/32/64 exact)
static __device__ __forceinline__ int rel_bucket(int rel /* k - q */) {
  int base = rel > 0 ? 16 : 0;
  int a = rel < 0 ? -rel : rel;
  if (a < 8) return base + a;
  int bl = 33 - __clz(a * a);     // = 8 + floor(2*log2(a) - 6)
  if (bl > 15) bl = 15;
  return base + bl;
}

// detect input dtype from grep_a (= ones): bf16 -> us[0]=0x3F80 ; fp32 -> us[0]=0x0000
static __device__ __forceinline__ int inputs_are_bf16(const void* grep_a_raw) {
  return ((const ushort_t*)grep_a_raw)[0] == 0x3F80u;
}

// ---------------- canonicalize all inputs to bf16 ----------------
// segs: query 4M | q_w 1M | k_w 1M | v_w 1M | out_w 1M | q_b 1K | k_b 1K | v_b 1K |
//       out_b 1K | rel_bias 512 | grep_w 512 | grep_b 8 | grep_a 16
__global__ __launch_bounds__(256) void convert_all(
    const void* s0, const void* s1, const void* s2, const void* s3, const void* s4,
    const void* s5, const void* s6, const void* s7, const void* s8, const void* s9,
    const void* s10, const void* s11, const void* s12, ushort_t* __restrict__ dst)
{
  const int cnt[13] = {4194304, 1048576, 1048576, 1048576, 1048576,
                       1024, 1024, 1024, 1024, 512, 512, 8, 16};
  const int off[13] = {0, 4194304, 5242880, 6291456, 7340032,
                       8388608, 8389632, 8390656, 8391680, 8392704, 8393216, 8393728, 8393736};
  const void* srcs[13] = {s0, s1, s2, s3, s4, s5, s6, s7, s8, s9, s10, s11, s12};
  const int seg = blockIdx.y;
  const int n = cnt[seg];
  int i0 = (blockIdx.x * 256 + threadIdx.x) * 4;
  if (i0 >= n) return;
  ushort_t* d = dst + off[seg];
  if (inputs_are_bf16(s12)) {
    const ushort_t* s = (const ushort_t*)srcs[seg];
    #pragma unroll
    for (int j = 0; j < 4; ++j) if (i0 + j < n) d[i0 + j] = s[i0 + j];
  } else {
    const float* s = (const float*)srcs[seg];
    #pragma unroll
    for (int j = 0; j < 4; ++j) if (i0 + j < n) d[i0 + j] = f2b(s[i0 + j]);
  }
}

// ---------------- QKV projection ----------------
// A (4096x1024) bf16, W (1024x1024) bf16. q -> fp32 (scaled), k/v -> bf16, layout (B,H,T,HD).
__global__ __launch_bounds__(256) void gemm_qkv(
    const ushort_t* __restrict__ A,
    const ushort_t* __restrict__ qw, const ushort_t* __restrict__ qb,
    const ushort_t* __restrict__ kw, const ushort_t* __restrict__ kb,
    const ushort_t* __restrict__ vw, const ushort_t* __restrict__ vb,
    float* __restrict__ qo, ushort_t* __restrict__ ko, ushort_t* __restrict__ vo)
{
  const int z = blockIdx.z;
  const ushort_t* W    = (z == 0) ? qw : (z == 1) ? kw : vw;
  const ushort_t* bias = (z == 0) ? qb : (z == 1) ? kb : vb;

  const int wave = threadIdx.x >> 6;
  const int lane = threadIdx.x & 63;
  const int row  = lane & 15, quad = lane >> 4;
  const int m0 = blockIdx.x * 64 + wave * 16;
  const int n0 = blockIdx.y * 64;

  const ushort_t* pa = A + (size_t)(m0 + row) * CDIM + quad * 8;
  const ushort_t* pb = W + (size_t)(n0 + row) * CDIM + quad * 8;

  f32x4 acc0 = {0.f, 0.f, 0.f, 0.f};
  f32x4 acc1 = acc0, acc2 = acc0, acc3 = acc0;
  for (int k = 0; k < CDIM; k += 32) {
    short8 a  = *(const short8*)(pa + k);
    short8 b0 = *(const short8*)(pb + k);
    short8 b1 = *(const short8*)(pb + 16 * CDIM + k);
    short8 b2 = *(const short8*)(pb + 32 * CDIM + k);
    short8 b3 = *(const short8*)(pb + 48 * CDIM + k);
    acc0 = __builtin_amdgcn_mfma_f32_16x16x32_bf16(a, b0, acc0, 0, 0, 0);
    acc1 = __builtin_amdgcn_mfma_f32_16x16x32_bf16(a, b1, acc1, 0, 0, 0);
    acc2 = __builtin_amdgcn_mfma_f32_16x16x32_bf16(a, b2, acc2, 0, 0, 0);
    acc3 = __builtin_amdgcn_mfma_f32_16x16x32_bf16(a, b3, acc3, 0, 0, 0);
  }
  f32x4 accs[4] = {acc0, acc1, acc2, acc3};
  // C/D layout: col = lane&15, row = quad*4 + r
  for (int j = 0; j < 4; ++j) {
    int n = n0 + j * 16 + row;
    float bv = b2f(bias[n]);
    int h = n >> 6, d = n & 63;
    for (int r = 0; r < 4; ++r) {
      int m = m0 + quad * 4 + r;
      int t = m >> 2, b = m & 3;                   // m = t*B + b
      size_t idx = (((size_t)(b * NHEAD + h)) * T_LEN + t) * HDIM + d;
      float v = accs[j][r] + bv;
      if (z == 0)      qo[idx] = v * 0.125f;       // HD^-0.5
      else if (z == 1) ko[idx] = f2b(v);
      else             vo[idx] = f2b(v);
    }
  }
}

// ---------------- attention: per block = (b,h, 8 q-rows); fp32 VALU ----------------
__global__ __launch_bounds__(256) void attn_kernel(
    const float* __restrict__ q, const ushort_t* __restrict__ k, const ushort_t* __restrict__ v,
    const ushort_t* __restrict__ rel_bias, const ushort_t* __restrict__ grep_w,
    const ushort_t* __restrict__ grep_b, const ushort_t* __restrict__ grep_a,
    ushort_t* __restrict__ attn_out)
{
  __shared__ float q_s[TQ][64];
  __shared__ float chunk_s[32][65];      // pad -> conflict-free
  __shared__ float score_s[TQ][1024];    // 32 KB
  __shared__ float bias_s[32];
  __shared__ float gate_s[TQ];
  __shared__ float gpre_s[TQ][8];
  __shared__ float red_s[TQ][32];
  __shared__ float m_s[TQ], l_s[TQ];

  const int tid = threadIdx.x;
  const int blk = blockIdx.x;            // bh*(T/TQ) + qt
  const int qt = blk & 127;
  const int bh = blk >> 7;               // 0..63
  const int h = bh & 15;
  const int bb = bh >> 4;
  const int q0 = qt * TQ;
  const float* qbase = q + ((size_t)bh * T_LEN + q0) * HDIM;
  const ushort_t* kbase = k + (size_t)bh * T_LEN * HDIM;
  const ushort_t* vbase = v + (size_t)bh * T_LEN * HDIM;

  for (int i = tid; i < TQ * 64; i += 256) q_s[i >> 6][i & 63] = qbase[i];
  if (tid < 32) bias_s[tid] = b2f(rel_bias[tid * NHEAD + h]);
  __syncthreads();

  if (tid < TQ * 8) {
    int r = tid >> 3, j = tid & 7;
    float s = b2f(grep_b[j]);
    for (int d = 0; d < 64; ++d) s += q_s[r][d] * b2f(grep_w[j * 64 + d]);
    gpre_s[r][j] = s;
  }
  __syncthreads();
  if (tid < TQ) {
    float ga = gpre_s[tid][0] + gpre_s[tid][1] + gpre_s[tid][2] + gpre_s[tid][3];
    float gb = gpre_s[tid][4] + gpre_s[tid][5] + gpre_s[tid][6] + gpre_s[tid][7];
    ga = 1.f / (1.f + expf(-ga));
    gb = 1.f / (1.f + expf(-gb));
    gate_s[tid] = ga * (gb * b2f(grep_a[h]) - 1.0f) + 2.0f;
  }

  // scores
  const int kj = tid & 31, rr = tid >> 5;
  for (int kc = 0; kc < T_LEN; kc += 32) {
    __syncthreads();
    const unsigned int* kptr = (const unsigned int*)(kbase + (size_t)kc * HDIM);
    for (int i = tid; i < 32 * 32; i += 256) {      // 1024 bf16-pairs
      unsigned int u = kptr[i];
      int rw = i >> 5, cl = (i & 31) * 2;
      chunk_s[rw][cl]     = b2f((ushort_t)(u & 0xffffu));
      chunk_s[rw][cl + 1] = b2f((ushort_t)(u >> 16));
    }
    __syncthreads();
    float s = 0.f;
    #pragma unroll 8
    for (int d = 0; d < 64; ++d) s += q_s[rr][d] * chunk_s[kj][d];
    int kg = kc + kj;
    int bkt = rel_bucket(kg - (q0 + rr));
    s += gate_s[rr] * bias_s[bkt];
    score_s[rr][kg] = s;
  }
  __syncthreads();

  // softmax (32 threads per row)
  {
    const int r = tid >> 5, j = tid & 31;
    float mx = -1e30f;
    for (int kk = j; kk < T_LEN; kk += 32) mx = fmaxf(mx, score_s[r][kk]);
    red_s[r][j] = mx;
    __syncthreads();
    if (j == 0) {
      float mm = red_s[r][0];
      #pragma unroll
      for (int i = 1; i < 32; ++i) mm = fmaxf(mm, red_s[r][i]);
      m_s[r] = mm;
    }
    __syncthreads();
    const float mm = m_s[r];
    float sum = 0.f;
    for (int kk = j; kk < T_LEN; kk += 32) {
      float p = expf(score_s[r][kk] - mm);
      score_s[r][kk] = p;
      sum += p;
    }
    red_s[r][j] = sum;
    __syncthreads();
    if (j == 0) {
      float ss = 0.f;
      for (int i = 0; i < 32; ++i) ss += red_s[r][i];
      l_s[r] = ss;
    }
  }

  // PV
  const int d = tid & 63, r0 = (tid >> 6) * 2;
  float acc0 = 0.f, acc1 = 0.f;
  for (int kc = 0; kc < T_LEN; kc += 32) {
    __syncthreads();
    const unsigned int* vptr = (const unsigned int*)(vbase + (size_t)kc * HDIM);
    for (int i = tid; i < 32 * 32; i += 256) {
      unsigned int u = vptr[i];
      int rw = i >> 5, cl = (i & 31) * 2;
      chunk_s[rw][cl]     = b2f((ushort_t)(u & 0xffffu));
      chunk_s[rw][cl + 1] = b2f((ushort_t)(u >> 16));
    }
    __syncthreads();
    #pragma unroll 8
    for (int kk = 0; kk < 32; ++kk) {
      float vv = chunk_s[kk][d];
      acc0 += score_s[r0][kc + kk] * vv;
      acc1 += score_s[r0 + 1][kc + kk] * vv;
    }
  }
  const float inv0 = 1.f / l_s[r0], inv1 = 1.f / l_s[r0 + 1];
  attn_out[((size_t)(q0 + r0) * BATCH + bb) * CDIM + h * HDIM + d] = f2b(acc0 * inv0);
  attn_out[((size_t)(q0 + r0 + 1) * BATCH + bb) * CDIM + h * HDIM + d] = f2b(acc1 * inv1);
}

// ---------------- output projection: d_out = A @ W^T + b ----------------
__global__ __launch_bounds__(256) void gemm_out(
    const ushort_t* __restrict__ A, const ushort_t* __restrict__ W,
    const ushort_t* __restrict__ bias, const void* __restrict__ ga_raw,
    void* __restrict__ out)
{
  const int wave = threadIdx.x >> 6;
  const int lane = threadIdx.x & 63;
  const int row  = lane & 15, quad = lane >> 4;
  const int m0 = blockIdx.x * 64 + wave * 16;
  const int n0 = blockIdx.y * 64;

  const ushort_t* pa = A + (size_t)(m0 + row) * CDIM + quad * 8;
  const ushort_t* pb = W + (size_t)(n0 + row) * CDIM + quad * 8;

  f32x4 acc0 = {0.f, 0.f, 0.f, 0.f};
  f32x4 acc1 = acc0, acc2 = acc0, acc3 = acc0;
  for (int k = 0; k < CDIM; k += 32) {
    short8 a  = *(const short8*)(pa + k);
    short8 b0 = *(const short8*)(pb + k);
    short8 b1 = *(const short8*)(pb + 16 * CDIM + k);
    short8 b2 = *(const short8*)(pb + 32 * CDIM + k);
    short8 b3 = *(const short8*)(pb + 48 * CDIM + k);
    acc0 = __builtin_amdgcn_mfma_f32_16x16x32_bf16(a, b0, acc0, 0, 0, 0);
    acc1 = __builtin_amdgcn_mfma_f32_16x16x32_bf16(a, b1, acc1, 0, 0, 0);
    acc2 = __builtin_amdgcn_mfma_f32_16x16x32_bf16(a, b2, acc2, 0, 0, 0);
    acc3 = __builtin_amdgcn_mfma_f32_16x16x32_bf16(a, b3, acc3, 0, 0, 0);
  }
  const int bf16out = inputs_are_bf16(ga_raw);
  f32x4 accs[4] = {acc0, acc1, acc2, acc3};
  for (int j = 0; j < 4; ++j) {
    int n = n0 + j * 16 + row;
    float bv = b2f(bias[n]);
    for (int r = 0; r < 4; ++r) {
      int m = m0 + quad * 4 + r;
      float val = accs[j][r] + bv;
      if (bf16out) ((ushort_t*)out)[(size_t)m * CDIM + n] = f2b(val);
      else         ((float*)out)[(size_t)m * CDIM + n] = val;
    }
  }
}

extern "C" void kernel_launch(void* const* d_in, const int* in_sizes, int n_in,
                              void* d_out, int out_size, void* d_ws, size_t ws_size,
                              hipStream_t stream) {
  const void* query  = d_in[0];
  const void* q_w    = d_in[1];
  const void* q_b    = d_in[2];
  const void* k_w    = d_in[3];
  const void* k_b    = d_in[4];
  const void* v_w    = d_in[5];
  const void* v_b    = d_in[6];
  const void* out_w  = d_in[7];
  const void* out_b  = d_in[8];
  const void* relb   = d_in[9];
  const void* grep_w = d_in[10];
  const void* grep_b = d_in[11];
  const void* grep_a = d_in[12];

  // ws (bytes): qf fp32 16MB | kf bf16 8MB | vf bf16 8MB | ao bf16 8MB | canonical bf16 ~16MB
  char* ws = (char*)d_ws;
  float*    qf = (float*)ws;
  ushort_t* kf = (ushort_t*)(ws + (size_t)16 * 1024 * 1024);
  ushort_t* vf = (ushort_t*)(ws + (size_t)24 * 1024 * 1024);
  ushort_t* ao = (ushort_t*)(ws + (size_t)32 * 1024 * 1024);
  ushort_t* cn = (ushort_t*)(ws + (size_t)40 * 1024 * 1024);

  ushort_t* cq   = cn;
  ushort_t* cqw  = cn + 4194304;
  ushort_t* ckw  = cn + 5242880;
  ushort_t* cvw  = cn + 6291456;
  ushort_t* cow  = cn + 7340032;
  ushort_t* cqb  = cn + 8388608;
  ushort_t* ckb  = cn + 8389632;
  ushort_t* cvb  = cn + 8390656;
  ushort_t* cob  = cn + 8391680;
  ushort_t* crb  = cn + 8392704;
  ushort_t* cgw  = cn + 8393216;
  ushort_t* cgb  = cn + 8393728;
  ushort_t* cga  = cn + 8393736;

  convert_all<<<dim3(4096, 13), dim3(256), 0, stream>>>(
      query, q_w, k_w, v_w, out_w, q_b, k_b, v_b, out_b, relb, grep_w, grep_b, grep_a, cn);
  gemm_qkv<<<dim3(64, 16, 3), dim3(256), 0, stream>>>(cq, cqw, cqb, ckw, ckb, cvw, cvb,
                                                      qf, kf, vf);
  attn_kernel<<<dim3(64 * (T_LEN / TQ)), dim3(256), 0, stream>>>(
      qf, kf, vf, crb, cgw, cgb, cga, ao);
  gemm_out<<<dim3(64, 16), dim3(256), 0, stream>>>(ao, cow, cob, grep_a, d_out);
}

// Round 4
// 522.513 us; speedup vs baseline: 3.2329x; 3.2329x over previous
//
#include <hip/hip_runtime.h>
#include <math.h>

typedef unsigned short ushort_t;
typedef __attribute__((ext_vector_type(8))) short short8;   // 8 bf16 in 4 VGPRs
typedef __attribute__((ext_vector_type(4))) float f32x4;

#define T_LEN 1024
#define BATCH 4
#define CDIM  1024
#define NHEAD 16
#define HDIM  64

static __device__ __forceinline__ float b2f(ushort_t u) {
  union { unsigned int i; float f; } x;
  x.i = ((unsigned int)u) << 16;
  return x.f;
}
// fp32 -> bf16 bits, round-to-nearest-even
static __device__ __forceinline__ ushort_t f2b(float f) {
  unsigned int x = __float_as_uint(f);
  unsigned int r = (x + 0x7fffu + ((x >> 16) & 1u)) >> 16;
  return (ushort_t)r;
}

// exact T5 bucket (verified vs fp32-log reference at all boundaries)
static __device__ __forceinline__ int rel_bucket(int rel /* k - q */) {
  int base = rel > 0 ? 16 : 0;
  int a = rel < 0 ? -rel : rel;
  if (a < 8) return base + a;
  int bl = 33 - __clz(a * a);     // = 8 + floor(2*log2(a) - 6)
  if (bl > 15) bl = 15;
  return base + bl;
}

// detect input dtype from grep_a (= ones): bf16 -> us[0]=0x3F80 ; fp32 -> us[0]=0x0000
static __device__ __forceinline__ int inputs_are_bf16(const void* grep_a_raw) {
  return ((const ushort_t*)grep_a_raw)[0] == 0x3F80u;
}

// ---------------- canonicalize all inputs to bf16 ----------------
__global__ __launch_bounds__(256) void convert_all(
    const void* s0, const void* s1, const void* s2, const void* s3, const void* s4,
    const void* s5, const void* s6, const void* s7, const void* s8, const void* s9,
    const void* s10, const void* s11, const void* s12, ushort_t* __restrict__ dst)
{
  const int cnt[13] = {4194304, 1048576, 1048576, 1048576, 1048576,
                       1024, 1024, 1024, 1024, 512, 512, 8, 16};
  const int off[13] = {0, 4194304, 5242880, 6291456, 7340032,
                       8388608, 8389632, 8390656, 8391680, 8392704, 8393216, 8393728, 8393736};
  const void* srcs[13] = {s0, s1, s2, s3, s4, s5, s6, s7, s8, s9, s10, s11, s12};
  const int seg = blockIdx.y;
  const int n = cnt[seg];
  int i0 = (blockIdx.x * 256 + threadIdx.x) * 4;
  if (i0 >= n) return;
  ushort_t* d = dst + off[seg];
  if (inputs_are_bf16(s12)) {
    const ushort_t* s = (const ushort_t*)srcs[seg];
    #pragma unroll
    for (int j = 0; j < 4; ++j) if (i0 + j < n) d[i0 + j] = s[i0 + j];
  } else {
    const float* s = (const float*)srcs[seg];
    #pragma unroll
    for (int j = 0; j < 4; ++j) if (i0 + j < n) d[i0 + j] = f2b(s[i0 + j]);
  }
}

// ---------------- QKV projection ----------------
// A (4096x1024) bf16, W (1024x1024) bf16.
// q -> bf16 (B,H,T,HD) scaled; k -> bf16 (B,H,T,HD); v -> bf16 TRANSPOSED (B,H,HD,T).
__global__ __launch_bounds__(256) void gemm_qkv(
    const ushort_t* __restrict__ A,
    const ushort_t* __restrict__ qw, const ushort_t* __restrict__ qb,
    const ushort_t* __restrict__ kw, const ushort_t* __restrict__ kb,
    const ushort_t* __restrict__ vw, const ushort_t* __restrict__ vb,
    ushort_t* __restrict__ qo, ushort_t* __restrict__ ko, ushort_t* __restrict__ vo)
{
  const int z = blockIdx.z;
  const ushort_t* W    = (z == 0) ? qw : (z == 1) ? kw : vw;
  const ushort_t* bias = (z == 0) ? qb : (z == 1) ? kb : vb;

  const int wave = threadIdx.x >> 6;
  const int lane = threadIdx.x & 63;
  const int row  = lane & 15, quad = lane >> 4;
  const int m0 = blockIdx.x * 64 + wave * 16;
  const int n0 = blockIdx.y * 64;

  const ushort_t* pa = A + (size_t)(m0 + row) * CDIM + quad * 8;
  const ushort_t* pb = W + (size_t)(n0 + row) * CDIM + quad * 8;

  f32x4 acc0 = {0.f, 0.f, 0.f, 0.f};
  f32x4 acc1 = acc0, acc2 = acc0, acc3 = acc0;
  for (int k = 0; k < CDIM; k += 32) {
    short8 a  = *(const short8*)(pa + k);
    short8 b0 = *(const short8*)(pb + k);
    short8 b1 = *(const short8*)(pb + 16 * CDIM + k);
    short8 b2 = *(const short8*)(pb + 32 * CDIM + k);
    short8 b3 = *(const short8*)(pb + 48 * CDIM + k);
    acc0 = __builtin_amdgcn_mfma_f32_16x16x32_bf16(a, b0, acc0, 0, 0, 0);
    acc1 = __builtin_amdgcn_mfma_f32_16x16x32_bf16(a, b1, acc1, 0, 0, 0);
    acc2 = __builtin_amdgcn_mfma_f32_16x16x32_bf16(a, b2, acc2, 0, 0, 0);
    acc3 = __builtin_amdgcn_mfma_f32_16x16x32_bf16(a, b3, acc3, 0, 0, 0);
  }
  f32x4 accs[4] = {acc0, acc1, acc2, acc3};
  for (int j = 0; j < 4; ++j) {
    int n = n0 + j * 16 + row;
    float bv = b2f(bias[n]);
    int h = n >> 6, d = n & 63;
    for (int r = 0; r < 4; ++r) {
      int m = m0 + quad * 4 + r;
      int t = m >> 2, b = m & 3;                   // m = t*B + b
      float v = accs[j][r] + bv;
      int bh = b * NHEAD + h;
      if (z == 0)      qo[((size_t)bh * T_LEN + t) * HDIM + d] = f2b(v * 0.125f);
      else if (z == 1) ko[((size_t)bh * T_LEN + t) * HDIM + d] = f2b(v);
      else             vo[((size_t)bh * HDIM + d) * T_LEN + t] = f2b(v);   // transposed
    }
  }
}

// ---------------- MFMA flash attention ----------------
// block = (bh, 64 q-rows); 4 waves, each owns 16 q-rows. grid = 64*16 = 1024.
__global__ __launch_bounds__(256) void attn_mfma(
    const ushort_t* __restrict__ q, const ushort_t* __restrict__ k,
    const ushort_t* __restrict__ vt,
    const ushort_t* __restrict__ rel_bias, const ushort_t* __restrict__ grep_w,
    const ushort_t* __restrict__ grep_b, const ushort_t* __restrict__ grep_a,
    ushort_t* __restrict__ attn_out)
{
  __shared__ __align__(16) float Plds[4][16][68];  // stride 68: 16B-aligned rows, 2-way banks
  __shared__ float gpa[64][4], gpb[64][4];
  __shared__ float gate_s[64];
  __shared__ float bias_s[32];

  const int tid = threadIdx.x;
  const int blk = blockIdx.x;          // bh*16 + qt
  const int qt = blk & 15;
  const int bh = blk >> 4;             // 0..63
  const int h = bh & 15, bb = bh >> 4;
  const int q0 = qt * 64;
  const ushort_t* qbase = q + (size_t)bh * T_LEN * HDIM;
  const ushort_t* kbase = k + (size_t)bh * T_LEN * HDIM;
  const ushort_t* vbase = vt + (size_t)bh * HDIM * T_LEN;

  if (tid < 32) bias_s[tid] = b2f(rel_bias[tid * NHEAD + h]);

  // gates: 4 threads per q-row, each computes one j and j+4 dot
  {
    int row = tid >> 2, jj = tid & 3;
    const ushort_t* qr = qbase + (size_t)(q0 + row) * HDIM;
    float sa = b2f(grep_b[jj]), sb = b2f(grep_b[jj + 4]);
    for (int d = 0; d < 64; ++d) {
      float qv = b2f(qr[d]);
      sa += qv * b2f(grep_w[jj * 64 + d]);
      sb += qv * b2f(grep_w[(jj + 4) * 64 + d]);
    }
    gpa[row][jj] = sa; gpb[row][jj] = sb;
  }
  __syncthreads();
  if (tid < 64) {
    float ga = gpa[tid][0] + gpa[tid][1] + gpa[tid][2] + gpa[tid][3];
    float gb = gpb[tid][0] + gpb[tid][1] + gpb[tid][2] + gpb[tid][3];
    ga = 1.f / (1.f + __expf(-ga));
    gb = 1.f / (1.f + __expf(-gb));
    gate_s[tid] = ga * (gb * b2f(grep_a[h]) - 1.0f) + 2.0f;
  }
  __syncthreads();

  const int wid = tid >> 6, lane = tid & 63;
  const int col = lane & 15, quad = lane >> 4;
  const int qw0 = q0 + wid * 16;

  // Q fragments (held all kernel): A[m=col][kdim=quad*8+j], two K=32 halves
  short8 qf0 = *(const short8*)(qbase + (size_t)(qw0 + col) * HDIM + quad * 8);
  short8 qf1 = *(const short8*)(qbase + (size_t)(qw0 + col) * HDIM + 32 + quad * 8);

  float gate_r[4];
  #pragma unroll
  for (int r = 0; r < 4; ++r) gate_r[r] = gate_s[wid * 16 + quad * 4 + r];

  float m_r[4] = {-1e30f, -1e30f, -1e30f, -1e30f};
  float l_r[4] = {0.f, 0.f, 0.f, 0.f};
  f32x4 O[4] = {};
  const f32x4 z4 = {0.f, 0.f, 0.f, 0.f};

  for (int kc = 0; kc < T_LEN; kc += 64) {
    // S = Q K^T for 16 q-rows x 64 keys
    f32x4 S[4];
    #pragma unroll
    for (int n = 0; n < 4; ++n) {
      const ushort_t* kp = kbase + (size_t)(kc + n * 16 + col) * HDIM + quad * 8;
      short8 kf0 = *(const short8*)(kp);
      short8 kf1 = *(const short8*)(kp + 32);
      f32x4 s = __builtin_amdgcn_mfma_f32_16x16x32_bf16(qf0, kf0, z4, 0, 0, 0);
      S[n]     = __builtin_amdgcn_mfma_f32_16x16x32_bf16(qf1, kf1, s, 0, 0, 0);
    }
    // gated position bias
    #pragma unroll
    for (int n = 0; n < 4; ++n) {
      int kcol = kc + n * 16 + col;
      #pragma unroll
      for (int r = 0; r < 4; ++r) {
        int bkt = rel_bucket(kcol - (qw0 + quad * 4 + r));
        S[n][r] += gate_r[r] * bias_s[bkt];
      }
    }
    // online softmax (rows = quad*4+r, reduce across 16 lanes of the quad-group)
    float tmax[4];
    #pragma unroll
    for (int r = 0; r < 4; ++r)
      tmax[r] = fmaxf(fmaxf(S[0][r], S[1][r]), fmaxf(S[2][r], S[3][r]));
    #pragma unroll
    for (int off = 1; off < 16; off <<= 1) {
      #pragma unroll
      for (int r = 0; r < 4; ++r) tmax[r] = fmaxf(tmax[r], __shfl_xor(tmax[r], off));
    }
    float alpha[4], tsum[4];
    #pragma unroll
    for (int r = 0; r < 4; ++r) {
      float mn = fmaxf(m_r[r], tmax[r]);
      alpha[r] = __expf(m_r[r] - mn);
      m_r[r] = mn;
    }
    #pragma unroll
    for (int r = 0; r < 4; ++r) {
      float p0 = __expf(S[0][r] - m_r[r]);
      float p1 = __expf(S[1][r] - m_r[r]);
      float p2 = __expf(S[2][r] - m_r[r]);
      float p3 = __expf(S[3][r] - m_r[r]);
      Plds[wid][quad * 4 + r][col]      = p0;
      Plds[wid][quad * 4 + r][16 + col] = p1;
      Plds[wid][quad * 4 + r][32 + col] = p2;
      Plds[wid][quad * 4 + r][48 + col] = p3;
      tsum[r] = (p0 + p1) + (p2 + p3);
    }
    #pragma unroll
    for (int off = 1; off < 16; off <<= 1) {
      #pragma unroll
      for (int r = 0; r < 4; ++r) tsum[r] += __shfl_xor(tsum[r], off);
    }
    #pragma unroll
    for (int r = 0; r < 4; ++r) l_r[r] = l_r[r] * alpha[r] + tsum[r];
    #pragma unroll
    for (int dd = 0; dd < 4; ++dd) {
      #pragma unroll
      for (int r = 0; r < 4; ++r) O[dd][r] *= alpha[r];
    }
    // P: C-layout -> A-layout via wave-private LDS (no barrier: wave-synchronous)
    short8 pf0, pf1;
    {
      const float* pr = &Plds[wid][col][quad * 8];
      #pragma unroll
      for (int j = 0; j < 8; ++j) pf0[j] = (short)f2b(pr[j]);
      const float* pr2 = &Plds[wid][col][32 + quad * 8];
      #pragma unroll
      for (int j = 0; j < 8; ++j) pf1[j] = (short)f2b(pr2[j]);
    }
    // O += P V  (B-frag rows = Vt rows = d)
    #pragma unroll
    for (int dd = 0; dd < 4; ++dd) {
      const ushort_t* vp = vbase + (size_t)(dd * 16 + col) * T_LEN + kc + quad * 8;
      short8 vf0 = *(const short8*)(vp);
      short8 vf1 = *(const short8*)(vp + 32);
      O[dd] = __builtin_amdgcn_mfma_f32_16x16x32_bf16(pf0, vf0, O[dd], 0, 0, 0);
      O[dd] = __builtin_amdgcn_mfma_f32_16x16x32_bf16(pf1, vf1, O[dd], 0, 0, 0);
    }
  }
  // epilogue: normalize, store to (T,B,C) bf16
  #pragma unroll
  for (int r = 0; r < 4; ++r) {
    float inv = 1.f / l_r[r];
    int t = qw0 + quad * 4 + r;
    #pragma unroll
    for (int dd = 0; dd < 4; ++dd)
      attn_out[((size_t)t * BATCH + bb) * CDIM + h * HDIM + dd * 16 + col] =
          f2b(O[dd][r] * inv);
  }
}

// ---------------- output projection: d_out = A @ W^T + b ----------------
__global__ __launch_bounds__(256) void gemm_out(
    const ushort_t* __restrict__ A, const ushort_t* __restrict__ W,
    const ushort_t* __restrict__ bias, const void* __restrict__ ga_raw,
    void* __restrict__ out)
{
  const int wave = threadIdx.x >> 6;
  const int lane = threadIdx.x & 63;
  const int row  = lane & 15, quad = lane >> 4;
  const int m0 = blockIdx.x * 64 + wave * 16;
  const int n0 = blockIdx.y * 64;

  const ushort_t* pa = A + (size_t)(m0 + row) * CDIM + quad * 8;
  const ushort_t* pb = W + (size_t)(n0 + row) * CDIM + quad * 8;

  f32x4 acc0 = {0.f, 0.f, 0.f, 0.f};
  f32x4 acc1 = acc0, acc2 = acc0, acc3 = acc0;
  for (int k = 0; k < CDIM; k += 32) {
    short8 a  = *(const short8*)(pa + k);
    short8 b0 = *(const short8*)(pb + k);
    short8 b1 = *(const short8*)(pb + 16 * CDIM + k);
    short8 b2 = *(const short8*)(pb + 32 * CDIM + k);
    short8 b3 = *(const short8*)(pb + 48 * CDIM + k);
    acc0 = __builtin_amdgcn_mfma_f32_16x16x32_bf16(a, b0, acc0, 0, 0, 0);
    acc1 = __builtin_amdgcn_mfma_f32_16x16x32_bf16(a, b1, acc1, 0, 0, 0);
    acc2 = __builtin_amdgcn_mfma_f32_16x16x32_bf16(a, b2, acc2, 0, 0, 0);
    acc3 = __builtin_amdgcn_mfma_f32_16x16x32_bf16(a, b3, acc3, 0, 0, 0);
  }
  const int bf16out = inputs_are_bf16(ga_raw);
  f32x4 accs[4] = {acc0, acc1, acc2, acc3};
  for (int j = 0; j < 4; ++j) {
    int n = n0 + j * 16 + row;
    float bv = b2f(bias[n]);
    for (int r = 0; r < 4; ++r) {
      int m = m0 + quad * 4 + r;
      float val = accs[j][r] + bv;
      if (bf16out) ((ushort_t*)out)[(size_t)m * CDIM + n] = f2b(val);
      else         ((float*)out)[(size_t)m * CDIM + n] = val;
    }
  }
}

extern "C" void kernel_launch(void* const* d_in, const int* in_sizes, int n_in,
                              void* d_out, int out_size, void* d_ws, size_t ws_size,
                              hipStream_t stream) {
  const void* query  = d_in[0];
  const void* q_w    = d_in[1];
  const void* q_b    = d_in[2];
  const void* k_w    = d_in[3];
  const void* k_b    = d_in[4];
  const void* v_w    = d_in[5];
  const void* v_b    = d_in[6];
  const void* out_w  = d_in[7];
  const void* out_b  = d_in[8];
  const void* relb   = d_in[9];
  const void* grep_w = d_in[10];
  const void* grep_b = d_in[11];
  const void* grep_a = d_in[12];

  // ws (bytes): q 8MB | k 8MB | vt 8MB | ao 8MB (all bf16) | canonical bf16 ~17MB
  char* ws = (char*)d_ws;
  ushort_t* qf = (ushort_t*)ws;
  ushort_t* kf = (ushort_t*)(ws + (size_t)8 * 1024 * 1024);
  ushort_t* vf = (ushort_t*)(ws + (size_t)16 * 1024 * 1024);
  ushort_t* ao = (ushort_t*)(ws + (size_t)24 * 1024 * 1024);
  ushort_t* cn = (ushort_t*)(ws + (size_t)32 * 1024 * 1024);

  ushort_t* cq   = cn;
  ushort_t* cqw  = cn + 4194304;
  ushort_t* ckw  = cn + 5242880;
  ushort_t* cvw  = cn + 6291456;
  ushort_t* cow  = cn + 7340032;
  ushort_t* cqb  = cn + 8388608;
  ushort_t* ckb  = cn + 8389632;
  ushort_t* cvb  = cn + 8390656;
  ushort_t* cob  = cn + 8391680;
  ushort_t* crb  = cn + 8392704;
  ushort_t* cgw  = cn + 8393216;
  ushort_t* cgb  = cn + 8393728;
  ushort_t* cga  = cn + 8393736;

  convert_all<<<dim3(4096, 13), dim3(256), 0, stream>>>(
      query, q_w, k_w, v_w, out_w, q_b, k_b, v_b, out_b, relb, grep_w, grep_b, grep_a, cn);
  gemm_qkv<<<dim3(64, 16, 3), dim3(256), 0, stream>>>(cq, cqw, cqb, ckw, ckb, cvw, cvb,
                                                      qf, kf, vf);
  attn_mfma<<<dim3(64 * 16), dim3(256), 0, stream>>>(
      qf, kf, vf, crb, cgw, cgb, cga, ao);
  gemm_out<<<dim3(64, 16), dim3(256), 0, stream>>>(ao, cow, cob, grep_a, d_out);
}

// Round 5
// 293.137 us; speedup vs baseline: 5.7626x; 1.7825x over previous
//
#include <hip/hip_runtime.h>
#include <math.h>

typedef unsigned short ushort_t;
typedef __attribute__((ext_vector_type(8))) short short8;   // 8 bf16 in 4 VGPRs
typedef __attribute__((ext_vector_type(4))) float f32x4;

#define T_LEN 1024
#define BATCH 4
#define CDIM  1024
#define NHEAD 16
#define HDIM  64

static __device__ __forceinline__ float b2f(ushort_t u) {
  union { unsigned int i; float f; } x;
  x.i = ((unsigned int)u) << 16;
  return x.f;
}
// fp32 -> bf16 bits, round-to-nearest-even
static __device__ __forceinline__ ushort_t f2b(float f) {
  unsigned int x = __float_as_uint(f);
  unsigned int r = (x + 0x7fffu + ((x >> 16) & 1u)) >> 16;
  return (ushort_t)r;
}

// exact T5 bucket (verified vs fp32-log reference at all boundaries)
static __device__ __forceinline__ int rel_bucket(int rel /* k - q */) {
  int base = rel > 0 ? 16 : 0;
  int a = rel < 0 ? -rel : rel;
  if (a < 8) return base + a;
  int bl = 33 - __clz(a * a);     // = 8 + floor(2*log2(a) - 6)
  if (bl > 15) bl = 15;
  return base + bl;
}

static __device__ __forceinline__ int inputs_are_bf16(const void* grep_a_raw) {
  return ((const ushort_t*)grep_a_raw)[0] == 0x3F80u;
}

// async 16B global -> LDS (lane-contiguous dest; guide §5, m97)
static __device__ __forceinline__ void async16(const ushort_t* g, ushort_t* l) {
  __builtin_amdgcn_global_load_lds(
      (const __attribute__((address_space(1))) unsigned int*)g,
      (__attribute__((address_space(3))) unsigned int*)l, 16, 0, 0);
}

// ---------------- canonicalize all inputs to bf16 ----------------
__global__ __launch_bounds__(256) void convert_all(
    const void* s0, const void* s1, const void* s2, const void* s3, const void* s4,
    const void* s5, const void* s6, const void* s7, const void* s8, const void* s9,
    const void* s10, const void* s11, const void* s12, ushort_t* __restrict__ dst)
{
  const int cnt[13] = {4194304, 1048576, 1048576, 1048576, 1048576,
                       1024, 1024, 1024, 1024, 512, 512, 8, 16};
  const int off[13] = {0, 4194304, 5242880, 6291456, 7340032,
                       8388608, 8389632, 8390656, 8391680, 8392704, 8393216, 8393728, 8393736};
  const void* srcs[13] = {s0, s1, s2, s3, s4, s5, s6, s7, s8, s9, s10, s11, s12};
  const int seg = blockIdx.y;
  const int n = cnt[seg];
  int i0 = (blockIdx.x * 256 + threadIdx.x) * 4;
  if (i0 >= n) return;
  ushort_t* d = dst + off[seg];
  if (inputs_are_bf16(s12)) {
    const ushort_t* s = (const ushort_t*)srcs[seg];
    #pragma unroll
    for (int j = 0; j < 4; ++j) if (i0 + j < n) d[i0 + j] = s[i0 + j];
  } else {
    const float* s = (const float*)srcs[seg];
    #pragma unroll
    for (int j = 0; j < 4; ++j) if (i0 + j < n) d[i0 + j] = f2b(s[i0 + j]);
  }
}

// ---------------- m97-style 128x128 tiled GEMM main loop (A,W both row-major K-contig) ----
// Asub/Bsub: 128x32 bf16, row-major, NO padding (global_load_lds lane-contiguity).
static __device__ __forceinline__ void gemm128_loop(
    const ushort_t* __restrict__ A, const ushort_t* __restrict__ W,
    int m0, int n0, ushort_t* Asub, ushort_t* Bsub, int tid, f32x4 acc[4][4])
{
  const int wid = tid >> 6, lane = tid & 63;
  const int wm = (wid & 1) * 64, wn = (wid >> 1) * 64;
  const int col = lane & 15, quad = lane >> 4;
  const int srow = tid >> 2;              // 0..63
  const int scol = (tid & 3) * 8;         // bf16 offset in 32-wide row

  const ushort_t* ga0 = A + (size_t)(m0 + srow) * CDIM + scol;
  const ushort_t* ga1 = A + (size_t)(m0 + 64 + srow) * CDIM + scol;
  const ushort_t* gb0 = W + (size_t)(n0 + srow) * CDIM + scol;
  const ushort_t* gb1 = W + (size_t)(n0 + 64 + srow) * CDIM + scol;
  ushort_t* la0 = Asub + tid * 8;
  ushort_t* la1 = Asub + 2048 + tid * 8;
  ushort_t* lb0 = Bsub + tid * 8;
  ushort_t* lb1 = Bsub + 2048 + tid * 8;

  for (int k = 0; k < CDIM; k += 32) {
    async16(ga0 + k, la0);
    async16(ga1 + k, la1);
    async16(gb0 + k, lb0);
    async16(gb1 + k, lb1);
    __syncthreads();                      // drains vmcnt (copies complete)
    short8 af[4], bf[4];
    #pragma unroll
    for (int i = 0; i < 4; ++i)
      af[i] = *(const short8*)&Asub[(wm + i * 16 + col) * 32 + quad * 8];
    #pragma unroll
    for (int i = 0; i < 4; ++i)
      bf[i] = *(const short8*)&Bsub[(wn + i * 16 + col) * 32 + quad * 8];
    #pragma unroll
    for (int mi = 0; mi < 4; ++mi)
      #pragma unroll
      for (int ni = 0; ni < 4; ++ni)
        acc[mi][ni] = __builtin_amdgcn_mfma_f32_16x16x32_bf16(af[mi], bf[ni], acc[mi][ni], 0, 0, 0);
    __syncthreads();                      // all reads done before next overwrite
  }
}

// ---------------- QKV projection (tiled) ----------------
// grid (M/128=32, N/128=8, 3). q -> bf16 (B,H,T,HD) scaled; k -> (B,H,T,HD); v -> (B,H,HD,T).
__global__ __launch_bounds__(256) void gemm_qkv(
    const ushort_t* __restrict__ A,
    const ushort_t* __restrict__ qw, const ushort_t* __restrict__ qb,
    const ushort_t* __restrict__ kw, const ushort_t* __restrict__ kb,
    const ushort_t* __restrict__ vw, const ushort_t* __restrict__ vb,
    ushort_t* __restrict__ qo, ushort_t* __restrict__ ko, ushort_t* __restrict__ vo)
{
  __shared__ __align__(16) ushort_t Asub[128 * 32];
  __shared__ __align__(16) ushort_t Bsub[128 * 32];
  const int z = blockIdx.z;
  const ushort_t* W    = (z == 0) ? qw : (z == 1) ? kw : vw;
  const ushort_t* bias = (z == 0) ? qb : (z == 1) ? kb : vb;

  const int tid = threadIdx.x;
  const int m0 = blockIdx.x * 128, n0 = blockIdx.y * 128;
  f32x4 acc[4][4] = {};
  gemm128_loop(A, W, m0, n0, Asub, Bsub, tid, acc);

  const int wid = tid >> 6, lane = tid & 63;
  const int wm = (wid & 1) * 64, wn = (wid >> 1) * 64;
  const int col = lane & 15, quad = lane >> 4;
  #pragma unroll
  for (int ni = 0; ni < 4; ++ni) {
    int n = n0 + wn + ni * 16 + col;
    float bv = b2f(bias[n]);
    int h = n >> 6, d = n & 63;
    #pragma unroll
    for (int mi = 0; mi < 4; ++mi) {
      #pragma unroll
      for (int r = 0; r < 4; ++r) {
        int m = m0 + wm + mi * 16 + quad * 4 + r;
        int t = m >> 2, b = m & 3;               // m = t*B + b
        float v = acc[mi][ni][r] + bv;
        int bh = b * NHEAD + h;
        if (z == 0)      qo[((size_t)bh * T_LEN + t) * HDIM + d] = f2b(v * 0.125f);
        else if (z == 1) ko[((size_t)bh * T_LEN + t) * HDIM + d] = f2b(v);
        else             vo[((size_t)bh * HDIM + d) * T_LEN + t] = f2b(v);  // transposed
      }
    }
  }
}

// ---------------- MFMA flash attention (unchanged from round 4, passing) ----------------
__global__ __launch_bounds__(256) void attn_mfma(
    const ushort_t* __restrict__ q, const ushort_t* __restrict__ k,
    const ushort_t* __restrict__ vt,
    const ushort_t* __restrict__ rel_bias, const ushort_t* __restrict__ grep_w,
    const ushort_t* __restrict__ grep_b, const ushort_t* __restrict__ grep_a,
    ushort_t* __restrict__ attn_out)
{
  __shared__ __align__(16) float Plds[4][16][68];
  __shared__ float gpa[64][4], gpb[64][4];
  __shared__ float gate_s[64];
  __shared__ float bias_s[32];

  const int tid = threadIdx.x;
  const int blk = blockIdx.x;
  const int qt = blk & 15;
  const int bh = blk >> 4;
  const int h = bh & 15, bb = bh >> 4;
  const int q0 = qt * 64;
  const ushort_t* qbase = q + (size_t)bh * T_LEN * HDIM;
  const ushort_t* kbase = k + (size_t)bh * T_LEN * HDIM;
  const ushort_t* vbase = vt + (size_t)bh * HDIM * T_LEN;

  if (tid < 32) bias_s[tid] = b2f(rel_bias[tid * NHEAD + h]);

  {
    int row = tid >> 2, jj = tid & 3;
    const ushort_t* qr = qbase + (size_t)(q0 + row) * HDIM;
    float sa = b2f(grep_b[jj]), sb = b2f(grep_b[jj + 4]);
    for (int d = 0; d < 64; ++d) {
      float qv = b2f(qr[d]);
      sa += qv * b2f(grep_w[jj * 64 + d]);
      sb += qv * b2f(grep_w[(jj + 4) * 64 + d]);
    }
    gpa[row][jj] = sa; gpb[row][jj] = sb;
  }
  __syncthreads();
  if (tid < 64) {
    float ga = gpa[tid][0] + gpa[tid][1] + gpa[tid][2] + gpa[tid][3];
    float gb = gpb[tid][0] + gpb[tid][1] + gpb[tid][2] + gpb[tid][3];
    ga = 1.f / (1.f + __expf(-ga));
    gb = 1.f / (1.f + __expf(-gb));
    gate_s[tid] = ga * (gb * b2f(grep_a[h]) - 1.0f) + 2.0f;
  }
  __syncthreads();

  const int wid = tid >> 6, lane = tid & 63;
  const int col = lane & 15, quad = lane >> 4;
  const int qw0 = q0 + wid * 16;

  short8 qf0 = *(const short8*)(qbase + (size_t)(qw0 + col) * HDIM + quad * 8);
  short8 qf1 = *(const short8*)(qbase + (size_t)(qw0 + col) * HDIM + 32 + quad * 8);

  float gate_r[4];
  #pragma unroll
  for (int r = 0; r < 4; ++r) gate_r[r] = gate_s[wid * 16 + quad * 4 + r];

  float m_r[4] = {-1e30f, -1e30f, -1e30f, -1e30f};
  float l_r[4] = {0.f, 0.f, 0.f, 0.f};
  f32x4 O[4] = {};
  const f32x4 z4 = {0.f, 0.f, 0.f, 0.f};

  for (int kc = 0; kc < T_LEN; kc += 64) {
    f32x4 S[4];
    #pragma unroll
    for (int n = 0; n < 4; ++n) {
      const ushort_t* kp = kbase + (size_t)(kc + n * 16 + col) * HDIM + quad * 8;
      short8 kf0 = *(const short8*)(kp);
      short8 kf1 = *(const short8*)(kp + 32);
      f32x4 s = __builtin_amdgcn_mfma_f32_16x16x32_bf16(qf0, kf0, z4, 0, 0, 0);
      S[n]     = __builtin_amdgcn_mfma_f32_16x16x32_bf16(qf1, kf1, s, 0, 0, 0);
    }
    #pragma unroll
    for (int n = 0; n < 4; ++n) {
      int kcol = kc + n * 16 + col;
      #pragma unroll
      for (int r = 0; r < 4; ++r) {
        int bkt = rel_bucket(kcol - (qw0 + quad * 4 + r));
        S[n][r] += gate_r[r] * bias_s[bkt];
      }
    }
    float tmax[4];
    #pragma unroll
    for (int r = 0; r < 4; ++r)
      tmax[r] = fmaxf(fmaxf(S[0][r], S[1][r]), fmaxf(S[2][r], S[3][r]));
    #pragma unroll
    for (int off = 1; off < 16; off <<= 1) {
      #pragma unroll
      for (int r = 0; r < 4; ++r) tmax[r] = fmaxf(tmax[r], __shfl_xor(tmax[r], off));
    }
    float alpha[4], tsum[4];
    #pragma unroll
    for (int r = 0; r < 4; ++r) {
      float mn = fmaxf(m_r[r], tmax[r]);
      alpha[r] = __expf(m_r[r] - mn);
      m_r[r] = mn;
    }
    #pragma unroll
    for (int r = 0; r < 4; ++r) {
      float p0 = __expf(S[0][r] - m_r[r]);
      float p1 = __expf(S[1][r] - m_r[r]);
      float p2 = __expf(S[2][r] - m_r[r]);
      float p3 = __expf(S[3][r] - m_r[r]);
      Plds[wid][quad * 4 + r][col]      = p0;
      Plds[wid][quad * 4 + r][16 + col] = p1;
      Plds[wid][quad * 4 + r][32 + col] = p2;
      Plds[wid][quad * 4 + r][48 + col] = p3;
      tsum[r] = (p0 + p1) + (p2 + p3);
    }
    #pragma unroll
    for (int off = 1; off < 16; off <<= 1) {
      #pragma unroll
      for (int r = 0; r < 4; ++r) tsum[r] += __shfl_xor(tsum[r], off);
    }
    #pragma unroll
    for (int r = 0; r < 4; ++r) l_r[r] = l_r[r] * alpha[r] + tsum[r];
    #pragma unroll
    for (int dd = 0; dd < 4; ++dd) {
      #pragma unroll
      for (int r = 0; r < 4; ++r) O[dd][r] *= alpha[r];
    }
    short8 pf0, pf1;
    {
      const float* pr = &Plds[wid][col][quad * 8];
      #pragma unroll
      for (int j = 0; j < 8; ++j) pf0[j] = (short)f2b(pr[j]);
      const float* pr2 = &Plds[wid][col][32 + quad * 8];
      #pragma unroll
      for (int j = 0; j < 8; ++j) pf1[j] = (short)f2b(pr2[j]);
    }
    #pragma unroll
    for (int dd = 0; dd < 4; ++dd) {
      const ushort_t* vp = vbase + (size_t)(dd * 16 + col) * T_LEN + kc + quad * 8;
      short8 vf0 = *(const short8*)(vp);
      short8 vf1 = *(const short8*)(vp + 32);
      O[dd] = __builtin_amdgcn_mfma_f32_16x16x32_bf16(pf0, vf0, O[dd], 0, 0, 0);
      O[dd] = __builtin_amdgcn_mfma_f32_16x16x32_bf16(pf1, vf1, O[dd], 0, 0, 0);
    }
  }
  #pragma unroll
  for (int r = 0; r < 4; ++r) {
    float inv = 1.f / l_r[r];
    int t = qw0 + quad * 4 + r;
    #pragma unroll
    for (int dd = 0; dd < 4; ++dd)
      attn_out[((size_t)t * BATCH + bb) * CDIM + h * HDIM + dd * 16 + col] =
          f2b(O[dd][r] * inv);
  }
}

// ---------------- output projection (tiled): d_out = A @ W^T + b ----------------
__global__ __launch_bounds__(256) void gemm_out(
    const ushort_t* __restrict__ A, const ushort_t* __restrict__ W,
    const ushort_t* __restrict__ bias, const void* __restrict__ ga_raw,
    void* __restrict__ out)
{
  __shared__ __align__(16) ushort_t Asub[128 * 32];
  __shared__ __align__(16) ushort_t Bsub[128 * 32];
  const int tid = threadIdx.x;
  const int m0 = blockIdx.x * 128, n0 = blockIdx.y * 128;
  f32x4 acc[4][4] = {};
  gemm128_loop(A, W, m0, n0, Asub, Bsub, tid, acc);

  const int bf16out = inputs_are_bf16(ga_raw);
  const int wid = tid >> 6, lane = tid & 63;
  const int wm = (wid & 1) * 64, wn = (wid >> 1) * 64;
  const int col = lane & 15, quad = lane >> 4;
  #pragma unroll
  for (int ni = 0; ni < 4; ++ni) {
    int n = n0 + wn + ni * 16 + col;
    float bv = b2f(bias[n]);
    #pragma unroll
    for (int mi = 0; mi < 4; ++mi) {
      #pragma unroll
      for (int r = 0; r < 4; ++r) {
        int m = m0 + wm + mi * 16 + quad * 4 + r;
        float val = acc[mi][ni][r] + bv;
        if (bf16out) ((ushort_t*)out)[(size_t)m * CDIM + n] = f2b(val);
        else         ((float*)out)[(size_t)m * CDIM + n] = val;
      }
    }
  }
}

extern "C" void kernel_launch(void* const* d_in, const int* in_sizes, int n_in,
                              void* d_out, int out_size, void* d_ws, size_t ws_size,
                              hipStream_t stream) {
  const void* query  = d_in[0];
  const void* q_w    = d_in[1];
  const void* q_b    = d_in[2];
  const void* k_w    = d_in[3];
  const void* k_b    = d_in[4];
  const void* v_w    = d_in[5];
  const void* v_b    = d_in[6];
  const void* out_w  = d_in[7];
  const void* out_b  = d_in[8];
  const void* relb   = d_in[9];
  const void* grep_w = d_in[10];
  const void* grep_b = d_in[11];
  const void* grep_a = d_in[12];

  // ws (bytes): q 8MB | k 8MB | vt 8MB | ao 8MB (all bf16) | canonical bf16 ~17MB
  char* ws = (char*)d_ws;
  ushort_t* qf = (ushort_t*)ws;
  ushort_t* kf = (ushort_t*)(ws + (size_t)8 * 1024 * 1024);
  ushort_t* vf = (ushort_t*)(ws + (size_t)16 * 1024 * 1024);
  ushort_t* ao = (ushort_t*)(ws + (size_t)24 * 1024 * 1024);
  ushort_t* cn = (ushort_t*)(ws + (size_t)32 * 1024 * 1024);

  ushort_t* cq   = cn;
  ushort_t* cqw  = cn + 4194304;
  ushort_t* ckw  = cn + 5242880;
  ushort_t* cvw  = cn + 6291456;
  ushort_t* cow  = cn + 7340032;
  ushort_t* cqb  = cn + 8388608;
  ushort_t* ckb  = cn + 8389632;
  ushort_t* cvb  = cn + 8390656;
  ushort_t* cob  = cn + 8391680;
  ushort_t* crb  = cn + 8392704;
  ushort_t* cgw  = cn + 8393216;
  ushort_t* cgb  = cn + 8393728;

  convert_all<<<dim3(4096, 13), dim3(256), 0, stream>>>(
      query, q_w, k_w, v_w, out_w, q_b, k_b, v_b, out_b, relb, grep_w, grep_b, grep_a, cn);
  gemm_qkv<<<dim3(32, 8, 3), dim3(256), 0, stream>>>(cq, cqw, cqb, ckw, ckb, cvw, cvb,
                                                     qf, kf, vf);
  attn_mfma<<<dim3(64 * 16), dim3(256), 0, stream>>>(
      qf, kf, vf, crb, cgw, cgb, cn + 8393736, ao);
  gemm_out<<<dim3(32, 8), dim3(256), 0, stream>>>(ao, cow, cob, grep_a, d_out);
}